// Round 3
// baseline (1074.011 us; speedup 1.0000x reference)
//
#include <hip/hip_runtime.h>
#include <cstdint>

#define SEQn   2048
#define NHn    16
#define HDn    128
#define DMn    2048   // NH*HD
#define HIDn   2048
#define BATCHn 2
#define WINn   256
#define MROWS  (BATCHn*SEQn)  // 4096

typedef short s16x8 __attribute__((ext_vector_type(8)));  // 8 bf16 (4 VGPRs)
typedef float f32x4 __attribute__((ext_vector_type(4)));  // MFMA accumulator

__device__ __forceinline__ float bf2f(ushort x) {
    union { uint u; float f; } v; v.u = ((uint)x) << 16; return v.f;
}
__device__ __forceinline__ ushort f2bf(float f) {
    union { float f; uint u; } v; v.f = f;
    uint u = v.u;
    return (ushort)((u + 0x7FFFu + ((u >> 16) & 1u)) >> 16);  // RNE
}

// ------- transpose+convert 2048x2048: W[k][n] fp32 -> WT[n][k] bf16 ----------
__global__ __launch_bounds__(256)
void transpose_cvt_kernel(const float* __restrict__ src, ushort* __restrict__ dst)
{
    __shared__ ushort t[32][33];
    const int tx = threadIdx.x, ty = threadIdx.y;
    const int n  = blockIdx.x * 32 + tx;
    const int k0 = blockIdx.y * 32;
    #pragma unroll
    for (int r = ty; r < 32; r += 8)
        t[r][tx] = f2bf(src[(size_t)(k0 + r) * 2048 + n]);
    __syncthreads();
    const int k  = k0 + tx;
    const int nb = blockIdx.x * 32;
    #pragma unroll
    for (int r = ty; r < 32; r += 8)
        dst[(size_t)(nb + r) * 2048 + k] = t[tx][r];
}

// ---------------- GEMM: C(MxN) = A(MxK) * BT(NxK)^T + bias ------------------
// A: fp32 (A_F32=1, converted to bf16 during LDS staging) or bf16 (A_F32=0).
// BT: bf16. C: fp32 (C_F32=1) or bf16 (C_F32=0). bias: fp32.
// 128x128 block tile, BK=64, 4 waves (2x2), wave tile 64x64 = 4x4 MFMA 16x16.
// C/D: col=lane&15, row=(lane>>4)*4+reg  (m89-verified mapping).
template<int A_F32, int C_F32>
__global__ __launch_bounds__(256)
void gemm_bt_kernel(const void* __restrict__ Araw, const ushort* __restrict__ BT,
                    const float* __restrict__ bias, void* __restrict__ Craw,
                    int M, int N, int K)
{
    __shared__ __align__(16) ushort As[128 * 72];
    __shared__ __align__(16) ushort Bs[128 * 72];
    const int tid = threadIdx.x;
    const int m0 = blockIdx.y * 128;
    const int n0 = blockIdx.x * 128;
    const int w  = tid >> 6;
    const int l  = tid & 63;
    const int wy = w >> 1, wx = w & 1;
    const int q  = l >> 4, lm = l & 15;

    f32x4 acc[4][4];
    #pragma unroll
    for (int i = 0; i < 4; ++i)
        #pragma unroll
        for (int j = 0; j < 4; ++j) acc[i][j] = (f32x4)0.0f;

    for (int kt = 0; kt < K; kt += 64) {
        #pragma unroll
        for (int it = 0; it < 4; ++it) {
            const int v = tid + it * 256;      // 0..1023 vec8 ids
            const int r = v >> 3;              // 0..127
            const int c = (v & 7) << 3;        // 0..56
            if (A_F32) {
                const float* Af = (const float*)Araw + (size_t)(m0 + r) * K + kt + c;
                const float4 a0 = *reinterpret_cast<const float4*>(Af);
                const float4 a1 = *reinterpret_cast<const float4*>(Af + 4);
                ushort* d = &As[r * 72 + c];
                d[0] = f2bf(a0.x); d[1] = f2bf(a0.y); d[2] = f2bf(a0.z); d[3] = f2bf(a0.w);
                d[4] = f2bf(a1.x); d[5] = f2bf(a1.y); d[6] = f2bf(a1.z); d[7] = f2bf(a1.w);
            } else {
                const uint4 av = *reinterpret_cast<const uint4*>(
                    (const ushort*)Araw + (size_t)(m0 + r) * K + kt + c);
                *reinterpret_cast<uint4*>(&As[r * 72 + c]) = av;
            }
            const uint4 bv = *reinterpret_cast<const uint4*>(BT + (size_t)(n0 + r) * K + kt + c);
            *reinterpret_cast<uint4*>(&Bs[r * 72 + c]) = bv;
        }
        __syncthreads();
        #pragma unroll
        for (int ks = 0; ks < 2; ++ks) {
            s16x8 af[4], bfv[4];
            #pragma unroll
            for (int im = 0; im < 4; ++im)
                af[im] = *reinterpret_cast<const s16x8*>(&As[(wy * 64 + im * 16 + lm) * 72 + ks * 32 + q * 8]);
            #pragma unroll
            for (int in = 0; in < 4; ++in)
                bfv[in] = *reinterpret_cast<const s16x8*>(&Bs[(wx * 64 + in * 16 + lm) * 72 + ks * 32 + q * 8]);
            #pragma unroll
            for (int im = 0; im < 4; ++im)
                #pragma unroll
                for (int in = 0; in < 4; ++in)
                    acc[im][in] = __builtin_amdgcn_mfma_f32_16x16x32_bf16(af[im], bfv[in], acc[im][in], 0, 0, 0);
        }
        __syncthreads();
    }
    #pragma unroll
    for (int in = 0; in < 4; ++in) {
        const int gcol = n0 + wx * 64 + in * 16 + lm;
        const float bv = bias[gcol];
        #pragma unroll
        for (int im = 0; im < 4; ++im) {
            const int grow0 = m0 + wy * 64 + im * 16 + q * 4;
            #pragma unroll
            for (int r = 0; r < 4; ++r) {
                const float val = acc[im][in][r] + bv;
                const size_t idx = (size_t)(grow0 + r) * N + gcol;
                if (C_F32) ((float*)Craw)[idx] = val;
                else       ((ushort*)Craw)[idx] = f2bf(val);
            }
        }
    }
}

// ---------------- RoPE in-place on Q and K (bf16): layout (B,S,NH,128) -------
__global__ __launch_bounds__(256)
void rope_kernel(ushort* Qb, ushort* Kb)
{
    const int idx = blockIdx.x * 256 + threadIdx.x;   // (b,s,h,d2), d2 in [0,64)
    ushort* buf = (blockIdx.z == 0) ? Qb : Kb;
    const int d2 = idx & 63;
    const int s  = (idx >> 10) & (SEQn - 1);
    const size_t base = ((size_t)(idx >> 6)) * 128 + d2;
    const float invf = powf(10000.0f, -(float)d2 * (1.0f / 64.0f));
    const float ang = (float)s * invf;
    const float c = cosf(ang), sn = sinf(ang);
    const float t1 = bf2f(buf[base]);
    const float t2 = bf2f(buf[base + 64]);
    buf[base]      = f2bf(t1 * c - t2 * sn);
    buf[base + 64] = f2bf(t1 * sn + t2 * c);
}

// ---------------- sliding-window attention: one wave per (b,h,i) -------------
// Q/K/V bf16; kw fp32. AO may alias Q (in-place): each wave reads exactly its
// own Q row at wave start and writes exactly the same slot at wave end.
__global__ __launch_bounds__(256)
void attn_kernel(const ushort* Q, const ushort* __restrict__ K,
                 const ushort* __restrict__ V, const float* __restrict__ kw,
                 ushort* AO)
{
    __shared__ __align__(16) float qs[4][128];
    __shared__ float ps[4][257];
    const int w = threadIdx.x >> 6;
    const int l = threadIdx.x & 63;
    const int gw = blockIdx.x * 4 + w;         // b(1b) | h(4b) | i(11b)
    const int i = gw & (SEQn - 1);
    const int h = (gw >> 11) & (NHn - 1);
    const int b = gw >> 15;
    const int jlo = max(0, i - WINn);
    const int nk = i - jlo + 1;                 // <= 257
    const float f = kw[h] * 0.08838834764831845f;  // * HD^-0.5
    const size_t rowQ = ((size_t)(b * SEQn + i)) * DMn + h * HDn;
    qs[w][l]      = bf2f(Q[rowQ + l]);
    qs[w][l + 64] = bf2f(Q[rowQ + l + 64]);
    __syncthreads();

    float sv[5] = {-1e30f, -1e30f, -1e30f, -1e30f, -1e30f};
    float mloc = -1e30f;
    const int nit = (nk + 63) >> 6;
    for (int it = 0; it < nit; ++it) {
        const int j = jlo + l + it * 64;
        if (j <= i) {
            const ushort* kr = K + ((size_t)(b * SEQn + j)) * DMn + h * HDn;
            float dot = 0.f;
            #pragma unroll
            for (int dd = 0; dd < 128; dd += 4) {
                const float4  q4 = *reinterpret_cast<const float4*>(&qs[w][dd]);
                const ushort4 k4 = *reinterpret_cast<const ushort4*>(kr + dd);
                dot = fmaf(q4.x, bf2f(k4.x), dot);
                dot = fmaf(q4.y, bf2f(k4.y), dot);
                dot = fmaf(q4.z, bf2f(k4.z), dot);
                dot = fmaf(q4.w, bf2f(k4.w), dot);
            }
            sv[it] = dot * f;
            mloc = fmaxf(mloc, sv[it]);
        }
    }
    #pragma unroll
    for (int off = 32; off > 0; off >>= 1)
        mloc = fmaxf(mloc, __shfl_xor(mloc, off));
    float lsum = 0.f;
    for (int it = 0; it < nit; ++it) {
        const int j = jlo + l + it * 64;
        if (j <= i) {
            const float p = __expf(sv[it] - mloc);
            ps[w][l + it * 64] = p;
            lsum += p;
        }
    }
    #pragma unroll
    for (int off = 32; off > 0; off >>= 1)
        lsum += __shfl_xor(lsum, off);
    const float inv = 1.0f / lsum;
    __syncthreads();

    const int d0 = l * 2;
    float a0 = 0.f, a1 = 0.f;
    const ushort* vbase = V + ((size_t)(b * SEQn + jlo)) * DMn + h * HDn + d0;
    for (int jj = 0; jj < nk; ++jj) {
        const float p = ps[w][jj];
        const ushort2 v2 = *reinterpret_cast<const ushort2*>(vbase + (size_t)jj * DMn);
        a0 = fmaf(p, bf2f(v2.x), a0);
        a1 = fmaf(p, bf2f(v2.y), a1);
    }
    const size_t orow = ((size_t)(b * SEQn + i)) * DMn + h * HDn + d0;
    AO[orow]     = f2bf(a0 * inv);
    AO[orow + 1] = f2bf(a1 * inv);
}

extern "C" void kernel_launch(void* const* d_in, const int* in_sizes, int n_in,
                              void* d_out, int out_size, void* d_ws, size_t ws_size,
                              hipStream_t stream)
{
    (void)in_sizes; (void)n_in; (void)out_size; (void)ws_size;
    // Reference dtypes are ALL float32 (setup_inputs uses jnp.float32).
    const float* x  = (const float*)d_in[0];
    const float* WQ = (const float*)d_in[1];
    const float* bQ = (const float*)d_in[2];
    const float* WK = (const float*)d_in[3];
    const float* bK = (const float*)d_in[4];
    const float* WV = (const float*)d_in[5];
    const float* bV = (const float*)d_in[6];
    const float* WO = (const float*)d_in[7];
    const float* bO = (const float*)d_in[8];
    const float* kw = (const float*)d_in[9];
    float* out = (float*)d_out;

    // Workspace layout — peak 56 MB (Qb/Kb/Vb bf16 16 MB each + one 8 MB WT).
    char* ws = (char*)d_ws;
    const size_t AELEMS = (size_t)MROWS * DMn;         // 4096*2048
    ushort* Qb = (ushort*)ws;                          // also used as AO (in-place)
    ushort* Kb = (ushort*)(ws + AELEMS * 2);
    ushort* Vb = (ushort*)(ws + AELEMS * 4);
    ushort* WT = (ushort*)(ws + AELEMS * 6);           // reused for all 4 weights

    const dim3 tgrid(64, 64);
    const dim3 tblk(32, 8);
    const dim3 ggrid(DMn / 128, MROWS / 128);          // 16 x 32

    transpose_cvt_kernel<<<tgrid, tblk, 0, stream>>>(WQ, WT);
    gemm_bt_kernel<1, 0><<<ggrid, 256, 0, stream>>>(x, WT, bQ, Qb, MROWS, DMn, HIDn);

    transpose_cvt_kernel<<<tgrid, tblk, 0, stream>>>(WK, WT);
    gemm_bt_kernel<1, 0><<<ggrid, 256, 0, stream>>>(x, WT, bK, Kb, MROWS, DMn, HIDn);

    transpose_cvt_kernel<<<tgrid, tblk, 0, stream>>>(WV, WT);
    gemm_bt_kernel<1, 0><<<ggrid, 256, 0, stream>>>(x, WT, bV, Vb, MROWS, DMn, HIDn);

    rope_kernel<<<dim3((BATCHn * SEQn * NHn * 64) / 256, 1, 2), 256, 0, stream>>>(Qb, Kb);

    attn_kernel<<<dim3((BATCHn * NHn * SEQn) / 4), 256, 0, stream>>>(Qb, Kb, Vb, kw, Qb);

    transpose_cvt_kernel<<<tgrid, tblk, 0, stream>>>(WO, WT);
    gemm_bt_kernel<0, 1><<<ggrid, 256, 0, stream>>>(Qb, WT, bO, out, MROWS, HIDn, DMn);
}

// Round 4
// 487.909 us; speedup vs baseline: 2.2013x; 2.2013x over previous
//
#include <hip/hip_runtime.h>
#include <cstdint>

#define SEQn   2048
#define NHn    16
#define HDn    128
#define DMn    2048   // NH*HD
#define HIDn   2048
#define BATCHn 2
#define WINn   256
#define MROWS  (BATCHn*SEQn)  // 4096

typedef short s16x8 __attribute__((ext_vector_type(8)));  // 8 bf16 (4 VGPRs)
typedef float f32x4 __attribute__((ext_vector_type(4)));  // MFMA accumulator

__device__ __forceinline__ float bf2f(ushort x) {
    union { uint u; float f; } v; v.u = ((uint)x) << 16; return v.f;
}
__device__ __forceinline__ ushort f2bf(float f) {
    union { float f; uint u; } v; v.f = f;
    uint u = v.u;
    return (ushort)((u + 0x7FFFu + ((u >> 16) & 1u)) >> 16);  // RNE
}

// ------- transpose+convert 2048x2048: W[k][n] fp32 -> WT[n][k] bf16 ----------
__global__ __launch_bounds__(256)
void transpose_cvt_kernel(const float* __restrict__ src, ushort* __restrict__ dst)
{
    __shared__ ushort t[32][33];
    const int tx = threadIdx.x, ty = threadIdx.y;
    const int n  = blockIdx.x * 32 + tx;
    const int k0 = blockIdx.y * 32;
    #pragma unroll
    for (int r = ty; r < 32; r += 8)
        t[r][tx] = f2bf(src[(size_t)(k0 + r) * 2048 + n]);
    __syncthreads();
    const int k  = k0 + tx;
    const int nb = blockIdx.x * 32;
    #pragma unroll
    for (int r = ty; r < 32; r += 8)
        dst[(size_t)(nb + r) * 2048 + k] = t[tx][r];
}

// ---------------- GEMM: C(MxN) = A(MxK) * BT(NxK)^T + bias ------------------
// A: fp32 (A_F32=1, converted to bf16 during LDS staging) or bf16 (A_F32=0).
// BT: bf16. C_MODE: 0 = bf16 row-major, 1 = fp32 row-major,
//            2 = bf16 Vt layout [b][h][d][s] (V GEMM writes transposed V).
// 128x128 block tile, BK=64, 4 waves (2x2), wave tile 64x64 = 4x4 MFMA 16x16.
// C/D: col=lane&15, row=(lane>>4)*4+reg  (m89-verified mapping).
template<int A_F32, int C_MODE>
__global__ __launch_bounds__(256)
void gemm_bt_kernel(const void* __restrict__ Araw, const ushort* __restrict__ BT,
                    const float* __restrict__ bias, void* __restrict__ Craw,
                    int M, int N, int K)
{
    __shared__ __align__(16) ushort As[128 * 72];
    __shared__ __align__(16) ushort Bs[128 * 72];
    const int tid = threadIdx.x;
    const int m0 = blockIdx.y * 128;
    const int n0 = blockIdx.x * 128;
    const int w  = tid >> 6;
    const int l  = tid & 63;
    const int wy = w >> 1, wx = w & 1;
    const int q  = l >> 4, lm = l & 15;

    f32x4 acc[4][4];
    #pragma unroll
    for (int i = 0; i < 4; ++i)
        #pragma unroll
        for (int j = 0; j < 4; ++j) acc[i][j] = (f32x4)0.0f;

    for (int kt = 0; kt < K; kt += 64) {
        #pragma unroll
        for (int it = 0; it < 4; ++it) {
            const int v = tid + it * 256;      // 0..1023 vec8 ids
            const int r = v >> 3;              // 0..127
            const int c = (v & 7) << 3;        // 0..56
            if (A_F32) {
                const float* Af = (const float*)Araw + (size_t)(m0 + r) * K + kt + c;
                const float4 a0 = *reinterpret_cast<const float4*>(Af);
                const float4 a1 = *reinterpret_cast<const float4*>(Af + 4);
                ushort* d = &As[r * 72 + c];
                d[0] = f2bf(a0.x); d[1] = f2bf(a0.y); d[2] = f2bf(a0.z); d[3] = f2bf(a0.w);
                d[4] = f2bf(a1.x); d[5] = f2bf(a1.y); d[6] = f2bf(a1.z); d[7] = f2bf(a1.w);
            } else {
                const uint4 av = *reinterpret_cast<const uint4*>(
                    (const ushort*)Araw + (size_t)(m0 + r) * K + kt + c);
                *reinterpret_cast<uint4*>(&As[r * 72 + c]) = av;
            }
            const uint4 bv = *reinterpret_cast<const uint4*>(BT + (size_t)(n0 + r) * K + kt + c);
            *reinterpret_cast<uint4*>(&Bs[r * 72 + c]) = bv;
        }
        __syncthreads();
        #pragma unroll
        for (int ks = 0; ks < 2; ++ks) {
            s16x8 af[4], bfv[4];
            #pragma unroll
            for (int im = 0; im < 4; ++im)
                af[im] = *reinterpret_cast<const s16x8*>(&As[(wy * 64 + im * 16 + lm) * 72 + ks * 32 + q * 8]);
            #pragma unroll
            for (int in = 0; in < 4; ++in)
                bfv[in] = *reinterpret_cast<const s16x8*>(&Bs[(wx * 64 + in * 16 + lm) * 72 + ks * 32 + q * 8]);
            #pragma unroll
            for (int im = 0; im < 4; ++im)
                #pragma unroll
                for (int in = 0; in < 4; ++in)
                    acc[im][in] = __builtin_amdgcn_mfma_f32_16x16x32_bf16(af[im], bfv[in], acc[im][in], 0, 0, 0);
        }
        __syncthreads();
    }
    #pragma unroll
    for (int in = 0; in < 4; ++in) {
        const int gcol = n0 + wx * 64 + in * 16 + lm;
        const float bv = bias[gcol];
        #pragma unroll
        for (int im = 0; im < 4; ++im) {
            const int grow0 = m0 + wy * 64 + im * 16 + q * 4;
            #pragma unroll
            for (int r = 0; r < 4; ++r) {
                const float val = acc[im][in][r] + bv;
                const int grow = grow0 + r;
                if (C_MODE == 0) {
                    ((ushort*)Craw)[(size_t)grow * N + gcol] = f2bf(val);
                } else if (C_MODE == 1) {
                    ((float*)Craw)[(size_t)grow * N + gcol] = val;
                } else {
                    // Vt[b][h][d][s]: b=grow>>11, s=grow&2047, h=gcol>>7, d=gcol&127
                    const int bb = grow >> 11, s = grow & (SEQn - 1);
                    const int hh = gcol >> 7,  d = gcol & (HDn - 1);
                    ((ushort*)Craw)[(((size_t)(bb * NHn + hh)) * HDn + d) * SEQn + s] = f2bf(val);
                }
            }
        }
    }
}

// ---------------- RoPE in-place on Q and K (bf16): layout (B,S,NH,128) -------
__global__ __launch_bounds__(256)
void rope_kernel(ushort* Qb, ushort* Kb)
{
    const int idx = blockIdx.x * 256 + threadIdx.x;   // (b,s,h,d2), d2 in [0,64)
    ushort* buf = (blockIdx.z == 0) ? Qb : Kb;
    const int d2 = idx & 63;
    const int s  = (idx >> 10) & (SEQn - 1);
    const size_t base = ((size_t)(idx >> 6)) * 128 + d2;
    const float invf = powf(10000.0f, -(float)d2 * (1.0f / 64.0f));
    const float ang = (float)s * invf;
    const float c = cosf(ang), sn = sinf(ang);
    const float t1 = bf2f(buf[base]);
    const float t2 = bf2f(buf[base + 64]);
    buf[base]      = f2bf(t1 * c - t2 * sn);
    buf[base + 64] = f2bf(t1 * sn + t2 * c);
}

// -------- MFMA flash attention: one wave per (b, h, 16-query tile) ----------
// Q: bf16 [b][s][h][d] (rope'd). K: bf16 [b][s][h][d] (rope'd).
// Vt: bf16 [b][h][d][s] (written transposed by the V GEMM epilogue).
// AO aliases Q in-place: each wave reads only its own 16 Q rows at start and
// writes exactly those rows at end (no other wave reads them).
__global__ __launch_bounds__(256)
void attn_mfma_kernel(const ushort* Q, const ushort* __restrict__ K,
                      const ushort* __restrict__ Vt, const float* __restrict__ kw,
                      ushort* AO)
{
    __shared__ ushort plds[4][16 * 40];   // per-wave P tile, stride 40 (2-way banks = free)
    const int w  = threadIdx.x >> 6;
    const int l  = threadIdx.x & 63;
    const int q  = l >> 4, lm = l & 15;
    const int gw = blockIdx.x * 4 + w;     // b(1) | h(4) | qt(7)
    const int qt = gw & 127;
    const int h  = (gw >> 7) & (NHn - 1);
    const int b  = gw >> 11;
    const int q0 = qt * 16;
    const float f = kw[h] * 0.08838834764831845f;   // kw * HD^-0.5

    // Q A-frags (m=lm query row, k=dim): frag[ks] covers dims [ks*32, ks*32+32)
    s16x8 qf[4];
    const size_t qbase = ((size_t)(b * SEQn + q0 + lm)) * DMn + h * HDn;
    #pragma unroll
    for (int ks = 0; ks < 4; ++ks)
        qf[ks] = *reinterpret_cast<const s16x8*>(Q + qbase + ks * 32 + q * 8);

    f32x4 O[8];
    #pragma unroll
    for (int nt = 0; nt < 8; ++nt) O[nt] = (f32x4)0.0f;
    float m[4]    = {-1e30f, -1e30f, -1e30f, -1e30f};
    float lsum[4] = {0.f, 0.f, 0.f, 0.f};

    const int lo = q0 - WINn;
    const int c0 = lo > 0 ? (lo & ~31) : 0;
    const int nch = (q0 + 16 - c0 + 31) >> 5;

    const size_t kbh = ((size_t)(b * SEQn)) * DMn + h * HDn;
    const size_t vbh = ((size_t)(b * NHn + h)) * HDn * SEQn;

    for (int c = 0; c < nch; ++c) {
        const int kc = c0 + c * 32;
        // ---- QK^T: two 16-key tiles, 4 chained k-MFMAs each ----
        f32x4 S[2];
        #pragma unroll
        for (int t = 0; t < 2; ++t) {
            f32x4 acc = (f32x4)0.0f;
            const size_t krow = kbh + (size_t)(kc + t * 16 + lm) * DMn;
            #pragma unroll
            for (int ks = 0; ks < 4; ++ks) {
                const s16x8 kf = *reinterpret_cast<const s16x8*>(K + krow + ks * 32 + q * 8);
                acc = __builtin_amdgcn_mfma_f32_16x16x32_bf16(qf[ks], kf, acc, 0, 0, 0);
            }
            S[t] = acc;
        }
        // ---- scale, mask, online softmax (rows live in 16-lane groups) ----
        const int j0 = kc + lm, j1 = kc + 16 + lm;
        #pragma unroll
        for (int r = 0; r < 4; ++r) {
            const int i = q0 + q * 4 + r;
            float v0 = S[0][r] * f;
            float v1 = S[1][r] * f;
            if (j0 > i || j0 < i - WINn) v0 = -1e30f;
            if (j1 > i || j1 < i - WINn) v1 = -1e30f;
            float mx = fmaxf(v0, v1);
            #pragma unroll
            for (int off = 8; off > 0; off >>= 1)
                mx = fmaxf(mx, __shfl_xor(mx, off));
            const float mn = fmaxf(m[r], mx);
            const float alpha = __expf(m[r] - mn);
            m[r] = mn;
            const ushort h0 = f2bf(__expf(v0 - mn));
            const ushort h1 = f2bf(__expf(v1 - mn));
            plds[w][(q * 4 + r) * 40 + lm]      = h0;
            plds[w][(q * 4 + r) * 40 + 16 + lm] = h1;
            float ps = bf2f(h0) + bf2f(h1);    // sum the bf16-rounded p's (consistency)
            #pragma unroll
            for (int off = 8; off > 0; off >>= 1)
                ps += __shfl_xor(ps, off);
            lsum[r] = lsum[r] * alpha + ps;
            #pragma unroll
            for (int nt = 0; nt < 8; ++nt) O[nt][r] *= alpha;
        }
        // ---- P (C/D layout) -> A-frag via per-wave LDS round trip ----
        const s16x8 pf = *reinterpret_cast<const s16x8*>(&plds[w][lm * 40 + q * 8]);
        // ---- P·V: 8 n-tiles of 16 dims, Vt key-contiguous vector loads ----
        #pragma unroll
        for (int nt = 0; nt < 8; ++nt) {
            const s16x8 vf = *reinterpret_cast<const s16x8*>(
                Vt + vbh + (size_t)(nt * 16 + lm) * SEQn + kc + q * 8);
            O[nt] = __builtin_amdgcn_mfma_f32_16x16x32_bf16(pf, vf, O[nt], 0, 0, 0);
        }
    }
    // ---- epilogue: O /= l, write rows q0+q*4+r ----
    #pragma unroll
    for (int r = 0; r < 4; ++r) {
        const float inv = 1.0f / lsum[r];
        const size_t orow = ((size_t)(b * SEQn + q0 + q * 4 + r)) * DMn + h * HDn;
        #pragma unroll
        for (int nt = 0; nt < 8; ++nt)
            AO[orow + nt * 16 + lm] = f2bf(O[nt][r] * inv);
    }
}

extern "C" void kernel_launch(void* const* d_in, const int* in_sizes, int n_in,
                              void* d_out, int out_size, void* d_ws, size_t ws_size,
                              hipStream_t stream)
{
    (void)in_sizes; (void)n_in; (void)out_size; (void)ws_size;
    const float* x  = (const float*)d_in[0];
    const float* WQ = (const float*)d_in[1];
    const float* bQ = (const float*)d_in[2];
    const float* WK = (const float*)d_in[3];
    const float* bK = (const float*)d_in[4];
    const float* WV = (const float*)d_in[5];
    const float* bV = (const float*)d_in[6];
    const float* WO = (const float*)d_in[7];
    const float* bO = (const float*)d_in[8];
    const float* kw = (const float*)d_in[9];
    float* out = (float*)d_out;

    // Workspace — peak 56 MB: Qb/Kb/Vt bf16 16 MB each + one 8 MB WT slot.
    char* ws = (char*)d_ws;
    const size_t AELEMS = (size_t)MROWS * DMn;         // 4096*2048
    ushort* Qb = (ushort*)ws;                          // also AO (in-place)
    ushort* Kb = (ushort*)(ws + AELEMS * 2);
    ushort* Vt = (ushort*)(ws + AELEMS * 4);           // [b][h][d][s]
    ushort* WT = (ushort*)(ws + AELEMS * 6);           // reused for all 4 weights

    const dim3 tgrid(64, 64);
    const dim3 tblk(32, 8);
    const dim3 ggrid(DMn / 128, MROWS / 128);          // 16 x 32

    transpose_cvt_kernel<<<tgrid, tblk, 0, stream>>>(WQ, WT);
    gemm_bt_kernel<1, 0><<<ggrid, 256, 0, stream>>>(x, WT, bQ, Qb, MROWS, DMn, HIDn);

    transpose_cvt_kernel<<<tgrid, tblk, 0, stream>>>(WK, WT);
    gemm_bt_kernel<1, 0><<<ggrid, 256, 0, stream>>>(x, WT, bK, Kb, MROWS, DMn, HIDn);

    transpose_cvt_kernel<<<tgrid, tblk, 0, stream>>>(WV, WT);
    gemm_bt_kernel<1, 2><<<ggrid, 256, 0, stream>>>(x, WT, bV, Vt, MROWS, DMn, HIDn);

    rope_kernel<<<dim3((BATCHn * SEQn * NHn * 64) / 256, 1, 2), 256, 0, stream>>>(Qb, Kb);

    attn_mfma_kernel<<<dim3((BATCHn * NHn * (SEQn / 16)) / 4), 256, 0, stream>>>(Qb, Kb, Vt, kw, Qb);

    transpose_cvt_kernel<<<tgrid, tblk, 0, stream>>>(WO, WT);
    gemm_bt_kernel<0, 1><<<ggrid, 256, 0, stream>>>(Qb, WT, bO, out, MROWS, HIDn, DMn);
}